// Round 13
// baseline (186.492 us; speedup 1.0000x reference)
//
#include <hip/hip_runtime.h>
#include <hip/hip_bf16.h>
#include <cmath>

// Problem constants
#define BATCH   16
#define SEQ     2048
#define IN_DIM  57
#define D_MODEL 64
#define HEADDIM 32
#define D_STATE 32
#define OUT_DIM 6
#define D_INNER 128
#define NHEADS  4
#define D_CONV  4
#define D_XBC   192          // D_INNER + 2*D_STATE
#define D_IN_PROJ 324        // 2*D_INNER + 2*D_STATE + NHEADS
#define BL      (BATCH*SEQ)  // 32768

// Chunked scan config
#define NCHUNK  128
#define CLEN    (SEQ / NCHUNK)   // 16
#define TROWS   (CLEN + 3)       // 19: chunk rows + 3-row conv halo

// Workspace layout (floats)
#define OFF_WF   ((size_t)0)                       // 57*324 (pad to 18496)
#define OFF_BF   ((size_t)18496)                   // 324
#define OFF_WOC  ((size_t)18848)                   // 768 (pad 896)
#define OFF_G    ((size_t)19744)                   // 2048
#define OFF_P    ((size_t)21792)                   // 64*128 = 8192 (pad 8224)
#define OFF_ZB   ((size_t)30016)                   // BL*128 z columns
#define OFF_XBT  (OFF_ZB  + (size_t)BL*D_INNER)    // BL*192 conv outputs
#define OFF_DD   (OFF_XBT + (size_t)BL*D_XBC)      // BL*8 {dt,dec}x4
#define OFF_SB   (OFF_DD  + (size_t)BL*8)          // 64*NCHUNK*1024 chunk states
// total ≈ 19.2M floats ≈ 77 MB

// Async global->LDS copy (gfx950): 16B per lane, wave-uniform LDS base.
typedef __attribute__((address_space(1))) const void gconst_void;
typedef __attribute__((address_space(3))) void lds_void;
__device__ __forceinline__ void async_copy16(const void* g, void* l) {
    __builtin_amdgcn_global_load_lds((gconst_void*)g, (lds_void*)l, 16, 0, 0);
}

// ---------------------------------------------------------------------------
// Kernel 1: Wf = W_lin@W_in ; bf = b_lin@W_in ; W_oc = W_out@W_cls
__global__ void fuse_w_kernel(const float* __restrict__ W_lin,
                              const float* __restrict__ b_lin,
                              const float* __restrict__ W_in,
                              const float* __restrict__ W_out,
                              const float* __restrict__ W_cls,
                              float* __restrict__ Wf, float* __restrict__ bf,
                              float* __restrict__ Woc) {
    int idx = blockIdx.x * 256 + threadIdx.x;
    if (idx < 58 * D_IN_PROJ) {
        int r = idx / D_IN_PROJ;
        int j = idx - r * D_IN_PROJ;
        const float* v = (r < IN_DIM) ? (W_lin + r * D_MODEL) : b_lin;
        float acc = 0.f;
#pragma unroll 8
        for (int m = 0; m < D_MODEL; ++m) acc += v[m] * W_in[m * D_IN_PROJ + j];
        if (r < IN_DIM) Wf[r * D_IN_PROJ + j] = acc;
        else            bf[j] = acc;
    } else if (idx < 58 * D_IN_PROJ + D_INNER * OUT_DIM) {
        int idx2 = idx - 58 * D_IN_PROJ;
        int i = idx2 / OUT_DIM;
        int o = idx2 - i * OUT_DIM;
        float acc = 0.f;
#pragma unroll 8
        for (int j = 0; j < D_MODEL; ++j)
            acc += W_out[i * D_MODEL + j] * W_cls[j * OUT_DIM + o];
        Woc[i * OUT_DIM + o] = acc;
    }
}

// ---------------------------------------------------------------------------
// FRONT kernel: fused in-projection + depthwise conv + dt/decay + phase-1
// B-scan. One block per (b, chunk). 19 x-rows staged in LDS (3-row halo),
// inproj computed in-block (z -> zb global; conv-input cols -> LDS only),
// conv+SiLU -> xbt LDS + xbtg global (for phase3), dt/dec -> ddl + ddc,
// then the B-scan emits the chunk state + decay product.
__global__ __launch_bounds__(256) void front_kernel(
        const float* __restrict__ x,
        const float* __restrict__ Wf,
        const float* __restrict__ bf,
        const float* __restrict__ conv_w, const float* __restrict__ conv_b,
        const float* __restrict__ dt_bias, const float* __restrict__ A_log,
        float* __restrict__ zb, float* __restrict__ xbtg,
        float* __restrict__ ddc,
        float* __restrict__ sbuf, float* __restrict__ Pbuf) {
    int b = blockIdx.x >> 7;          // NCHUNK=128
    int c = blockIdx.x & 127;
    int tid = threadIdx.x;
    __shared__ float xs[TROWS][60];        // 19 x-rows (240B stride, 16B-aligned)
    __shared__ float xdl[TROWS][196];      // inproj cols 128..323 (784B stride)
    __shared__ float xbt[CLEN][D_XBC];     // conv outputs
    __shared__ float ddl[CLEN][8];         // {dt,dec} x 4 heads
    size_t rbase = (size_t)b * SEQ + (size_t)c * CLEN;

    // Stage 1: load x rows l0-3 .. l0+15 (zero above sequence start)
    for (int idx = tid; idx < TROWS * IN_DIM; idx += 256) {
        int i = idx / IN_DIM, k = idx - i * IN_DIM;
        int l = c * CLEN + i - 3;
        xs[i][k] = (l >= 0) ? x[((size_t)b * SEQ + l) * IN_DIM + k] : 0.f;
    }
    __syncthreads();

    // Stage 2: in-projection.
    //  tid <  147: conv-input cols (g=32..80), 3 row-sets {7,6,6} over 19 rows.
    //  147<=tid<211: z cols (g=0..31), 2 row-sets of 8 over the 16 real rows.
    if (tid < 147) {
        int rset = tid / 49;
        int g = 32 + (tid - rset * 49);
        int j0 = g * 4;
        int row0 = (rset == 0) ? 0 : (rset == 1 ? 7 : 13);
        int nrows = (rset == 0) ? 7 : 6;
        float4 bias = *(const float4*)(bf + j0);
        float4 acc[7];
#pragma unroll
        for (int r = 0; r < 7; ++r) acc[r] = bias;
        const float* w = Wf + j0;
        for (int k = 0; k < IN_DIM; ++k) {
            float4 wv = *(const float4*)(w + (size_t)k * D_IN_PROJ);
#pragma unroll
            for (int r = 0; r < 7; ++r) {
                if (r < nrows) {
                    float xv = xs[row0 + r][k];
                    acc[r].x += xv * wv.x; acc[r].y += xv * wv.y;
                    acc[r].z += xv * wv.z; acc[r].w += xv * wv.w;
                }
            }
        }
        int off = j0 - D_INNER;
#pragma unroll
        for (int r = 0; r < 7; ++r) {
            if (r < nrows) {
                int row = row0 + r;
                float4 v = acc[r];
                if (c == 0 && row < 3) v = make_float4(0.f, 0.f, 0.f, 0.f);
                *(float4*)(&xdl[row][off]) = v;
            }
        }
    } else if (tid < 211) {
        int t = tid - 147;
        int rset = t >> 5;
        int g = t & 31;
        int j0 = g * 4;
        int row0 = 3 + rset * 8;          // tile rows 3..18 = real rows
        float4 bias = *(const float4*)(bf + j0);
        float4 acc[8];
#pragma unroll
        for (int r = 0; r < 8; ++r) acc[r] = bias;
        const float* w = Wf + j0;
        for (int k = 0; k < IN_DIM; ++k) {
            float4 wv = *(const float4*)(w + (size_t)k * D_IN_PROJ);
#pragma unroll
            for (int r = 0; r < 8; ++r) {
                float xv = xs[row0 + r][k];
                acc[r].x += xv * wv.x; acc[r].y += xv * wv.y;
                acc[r].z += xv * wv.z; acc[r].w += xv * wv.w;
            }
        }
#pragma unroll
        for (int r = 0; r < 8; ++r) {
            size_t l = rbase + (row0 - 3 + r);
            *(float4*)(zb + l * D_INNER + j0) = acc[r];
        }
    }
    __syncthreads();

    // Stage 3: conv + SiLU (LDS->LDS + global copy for phase3); dt/decay.
    if (tid < D_XBC) {
        int ch = tid;
        float w0 = conv_w[ch*4+0], w1 = conv_w[ch*4+1];
        float w2 = conv_w[ch*4+2], w3 = conv_w[ch*4+3];
        float cb = conv_b[ch];
        float vm3 = xdl[0][ch], vm2 = xdl[1][ch], vm1 = xdl[2][ch];
#pragma unroll
        for (int i = 0; i < CLEN; ++i) {
            float v0 = xdl[i + 3][ch];
            float a = cb + v0 * w3 + vm1 * w2 + vm2 * w1 + vm3 * w0;
            float sv = a / (1.f + expf(-a));   // SiLU
            xbt[i][ch] = sv;
            xbtg[(rbase + i) * D_XBC + ch] = sv;
            vm3 = vm2; vm2 = vm1; vm1 = v0;
        }
    } else {
        int idx = tid - D_XBC;       // 0..63
        int h = idx >> 4, i = idx & 15;
        float v = xdl[i + 3][192 + h] + dt_bias[h];
        float dtv = (v > 20.f) ? v : log1pf(expf(v));
        float dec = expf(dtv * -expf(A_log[h]));
        ddl[i][h * 2]     = dtv;
        ddl[i][h * 2 + 1] = dec;
        float* dd = ddc + (rbase + i) * 8 + h * 2;
        dd[0] = dtv;
        dd[1] = dec;
    }
    __syncthreads();

    // Stage 4: B-scan. Wave = head; lane -> (p = lane>>1, n-half=(lane&1)*16).
    int h = tid >> 6, lane = tid & 63;
    int p = lane >> 1, n0 = (lane & 1) * 16;
    float4 s0 = make_float4(0.f,0.f,0.f,0.f), s1 = s0, s2 = s0, s3 = s0;
    float pacc = 1.f;
#pragma unroll 4
    for (int i = 0; i < CLEN; ++i) {
        float dtv = ddl[i][h * 2];
        float dec = ddl[i][h * 2 + 1];
        float xv = xbt[i][h * HEADDIM + p];
        const float* Bp = &xbt[i][D_INNER + n0];
        float4 B0 = *(const float4*)(Bp + 0);
        float4 B1 = *(const float4*)(Bp + 4);
        float4 B2 = *(const float4*)(Bp + 8);
        float4 B3 = *(const float4*)(Bp + 12);
        float coef = dtv * xv;
        s0.x = s0.x*dec + coef*B0.x; s0.y = s0.y*dec + coef*B0.y;
        s0.z = s0.z*dec + coef*B0.z; s0.w = s0.w*dec + coef*B0.w;
        s1.x = s1.x*dec + coef*B1.x; s1.y = s1.y*dec + coef*B1.y;
        s1.z = s1.z*dec + coef*B1.z; s1.w = s1.w*dec + coef*B1.w;
        s2.x = s2.x*dec + coef*B2.x; s2.y = s2.y*dec + coef*B2.y;
        s2.z = s2.z*dec + coef*B2.z; s2.w = s2.w*dec + coef*B2.w;
        s3.x = s3.x*dec + coef*B3.x; s3.y = s3.y*dec + coef*B3.y;
        s3.z = s3.z*dec + coef*B3.z; s3.w = s3.w*dec + coef*B3.w;
        pacc *= dec;
    }
    int bh = b * NHEADS + h;
    float4* sp = (float4*)sbuf + ((size_t)bh * NCHUNK + c) * 256;
    sp[0*64 + lane] = s0;
    sp[1*64 + lane] = s1;
    sp[2*64 + lane] = s2;
    sp[3*64 + lane] = s3;
    if (lane == 0) Pbuf[bh * NCHUNK + c] = pacc;
}

// ---------------------------------------------------------------------------
// Phase 2: combine chunk states. Layout-agnostic per-(bh,c) slot scan.
__global__ __launch_bounds__(256) void scan_phase2_kernel(
        float* __restrict__ sbuf, const float* __restrict__ Pbuf) {
    int bh = blockIdx.x >> 2;
    int q  = blockIdx.x & 3;
    int idx = q * 256 + threadIdx.x;     // 0..1023
    float run = 0.f;
#pragma unroll 8
    for (int c = 0; c < NCHUNK; ++c) {
        size_t a = ((size_t)bh * NCHUNK + c) * 1024 + idx;
        float tmp = sbuf[a];
        float Pv = Pbuf[bh * NCHUNK + c];
        sbuf[a] = run;
        run = run * Pv + tmp;
    }
}

// ---------------------------------------------------------------------------
// Phase 3 (fused): async-staged xbt tile -> seeded scan from LDS -> y in LDS
// -> gate*silu(z) + RMSNorm + G accumulation.
__global__ __launch_bounds__(256) void scan_phase3_kernel(
        const float* __restrict__ xbtg, const float* __restrict__ ddc,
        const float* __restrict__ zb, const float* __restrict__ Dp,
        const float* __restrict__ sbuf, const float* __restrict__ norm_w,
        float* __restrict__ G) {
    int b = blockIdx.x >> 7;          // NCHUNK=128
    int c = blockIdx.x & 127;
    int h    = threadIdx.x >> 6;      // wave = head
    int lane = threadIdx.x & 63;
    int p  = lane >> 1;
    int n0 = (lane & 1) * 16;
    __shared__ float xt[CLEN][D_XBC];       // 12 KB, contiguous
    __shared__ float ylds[CLEN][D_INNER];   // 8 KB
    __shared__ float red[4][D_INNER];       // 2 KB
    size_t rbase = (size_t)b * SEQ + (size_t)c * CLEN;
    const char* gsrc = (const char*)(xbtg + rbase * D_XBC);
#pragma unroll
    for (int t = 0; t < 3; ++t) {
        int off = (h * 3 + t) * 1024;
        async_copy16(gsrc + off + lane * 16, (char*)(&xt[0][0]) + off);
    }
    // seed (global; overlaps with staging)
    int bh = b * NHEADS + h;
    const float4* sp = (const float4*)sbuf + ((size_t)bh * NCHUNK + c) * 256;
    float4 s0 = sp[0*64 + lane];
    float4 s1 = sp[1*64 + lane];
    float4 s2 = sp[2*64 + lane];
    float4 s3 = sp[3*64 + lane];
    float Dh = Dp[h];
    const float* dd = ddc + rbase * 8 + h * 2;
    __syncthreads();   // drains vmcnt before LDS reads
#pragma unroll 4
    for (int i = 0; i < CLEN; ++i) {
        float2 dv = *(const float2*)(dd + (size_t)i * 8);   // wave-uniform
        float xv = xt[i][h * HEADDIM + p];
        const float* Bp = &xt[i][D_INNER + n0];
        const float* Cp = &xt[i][D_INNER + D_STATE + n0];
        float4 B0 = *(const float4*)(Bp + 0);
        float4 B1 = *(const float4*)(Bp + 4);
        float4 B2 = *(const float4*)(Bp + 8);
        float4 B3 = *(const float4*)(Bp + 12);
        float4 C0 = *(const float4*)(Cp + 0);
        float4 C1 = *(const float4*)(Cp + 4);
        float4 C2 = *(const float4*)(Cp + 8);
        float4 C3 = *(const float4*)(Cp + 12);
        float coef = dv.x * xv;
        float dec  = dv.y;
        s0.x = s0.x*dec + coef*B0.x; s0.y = s0.y*dec + coef*B0.y;
        s0.z = s0.z*dec + coef*B0.z; s0.w = s0.w*dec + coef*B0.w;
        s1.x = s1.x*dec + coef*B1.x; s1.y = s1.y*dec + coef*B1.y;
        s1.z = s1.z*dec + coef*B1.z; s1.w = s1.w*dec + coef*B1.w;
        s2.x = s2.x*dec + coef*B2.x; s2.y = s2.y*dec + coef*B2.y;
        s2.z = s2.z*dec + coef*B2.z; s2.w = s2.w*dec + coef*B2.w;
        s3.x = s3.x*dec + coef*B3.x; s3.y = s3.y*dec + coef*B3.y;
        s3.z = s3.z*dec + coef*B3.z; s3.w = s3.w*dec + coef*B3.w;
        float part = s0.x*C0.x + s0.y*C0.y + s0.z*C0.z + s0.w*C0.w
                   + s1.x*C1.x + s1.y*C1.y + s1.z*C1.z + s1.w*C1.w
                   + s2.x*C2.x + s2.y*C2.y + s2.z*C2.z + s2.w*C2.w
                   + s3.x*C3.x + s3.y*C3.y + s3.z*C3.z + s3.w*C3.w;
        part += __shfl_xor(part, 1);
        if ((lane & 1) == 0)
            ylds[i][h * HEADDIM + p] = part + Dh * xv;
    }
    __syncthreads();
    // gate + RMSNorm from LDS; wave h handles rows r = h, h+4, ...
    float acc0 = 0.f, acc1 = 0.f;
    for (int r = h; r < CLEN; r += 4) {
        size_t bl = rbase + r;
        float2 yv = *(const float2*)(&ylds[r][lane * 2]);
        float2 zv = *(const float2*)(zb + bl * D_INNER + lane * 2);
        float g0 = yv.x * (zv.x / (1.f + expf(-zv.x)));
        float g1 = yv.y * (zv.y / (1.f + expf(-zv.y)));
        float sq = g0 * g0 + g1 * g1;
#pragma unroll
        for (int m = 1; m < 64; m <<= 1) sq += __shfl_xor(sq, m);
        float rms = 1.0f / sqrtf(sq * (1.f / 128.f) + 1e-5f);
        acc0 += g0 * rms;
        acc1 += g1 * rms;
    }
    red[h][lane * 2]     = acc0;
    red[h][lane * 2 + 1] = acc1;
    __syncthreads();
    int tid = threadIdx.x;
    if (tid < D_INNER) {
        float sg = red[0][tid] + red[1][tid] + red[2][tid] + red[3][tid];
        atomicAdd(&G[b * D_INNER + tid], sg * norm_w[tid]);
    }
}

// ---------------------------------------------------------------------------
// Kernel: out[b][o] = b_cls[o] + (G[b] @ W_oc)[o] / SEQ
__global__ void head_kernel(const float* __restrict__ G,
                            const float* __restrict__ Woc,
                            const float* __restrict__ b_cls,
                            float* __restrict__ out) {
    int tid = threadIdx.x;
    if (tid >= BATCH * OUT_DIM) return;
    int b = tid / OUT_DIM, o = tid - b * OUT_DIM;
    float acc = 0.f;
#pragma unroll 8
    for (int i = 0; i < D_INNER; ++i)
        acc += G[b * D_INNER + i] * Woc[i * OUT_DIM + o];
    out[b * OUT_DIM + o] = acc * (1.f / (float)SEQ) + b_cls[o];
}

// ---------------------------------------------------------------------------
extern "C" void kernel_launch(void* const* d_in, const int* in_sizes, int n_in,
                              void* d_out, int out_size, void* d_ws, size_t ws_size,
                              hipStream_t stream) {
    const float* x       = (const float*)d_in[0];
    const float* W_lin   = (const float*)d_in[1];
    const float* b_lin   = (const float*)d_in[2];
    const float* W_in    = (const float*)d_in[3];
    const float* conv_w  = (const float*)d_in[4];
    const float* conv_b  = (const float*)d_in[5];
    const float* dt_bias = (const float*)d_in[6];
    const float* A_log   = (const float*)d_in[7];
    const float* Dp      = (const float*)d_in[8];
    const float* norm_w  = (const float*)d_in[9];
    const float* W_out   = (const float*)d_in[10];
    const float* W_cls   = (const float*)d_in[11];
    const float* b_cls   = (const float*)d_in[12];
    float* out = (float*)d_out;

    float* ws = (float*)d_ws;
    float* Wf   = ws + OFF_WF;
    float* bf   = ws + OFF_BF;
    float* Woc  = ws + OFF_WOC;
    float* G    = ws + OFF_G;
    float* Pbuf = ws + OFF_P;
    float* zb   = ws + OFF_ZB;
    float* xbtg = ws + OFF_XBT;
    float* ddc  = ws + OFF_DD;
    float* sbuf = ws + OFF_SB;

    // zero the G accumulator (ws is poisoned before every call)
    hipMemsetAsync(G, 0, BATCH * D_INNER * sizeof(float), stream);

    // 1) fused weight precompute
    fuse_w_kernel<<<(58 * D_IN_PROJ + D_INNER * OUT_DIM + 255) / 256, 256, 0, stream>>>(
        W_lin, b_lin, W_in, W_out, W_cls, Wf, bf, Woc);

    // 2) FRONT: inproj + conv + dt + phase-1 B-scan (2048 blocks)
    front_kernel<<<BATCH * NCHUNK, 256, 0, stream>>>(
        x, Wf, bf, conv_w, conv_b, dt_bias, A_log,
        zb, xbtg, ddc, sbuf, Pbuf);

    // 3) chunk-state combine
    scan_phase2_kernel<<<64 * 4, 256, 0, stream>>>(sbuf, Pbuf);

    // 4) phase 3: seeded scan + gate + RMSNorm + G (async LDS staging)
    scan_phase3_kernel<<<BATCH * NCHUNK, 256, 0, stream>>>(
        xbtg, ddc, zb, Dp, sbuf, norm_w, G);

    // 5) classifier head
    head_kernel<<<1, 128, 0, stream>>>(G, Woc, b_cls, out);
}

// Round 14
// 183.125 us; speedup vs baseline: 1.0184x; 1.0184x over previous
//
#include <hip/hip_runtime.h>
#include <hip/hip_bf16.h>
#include <cmath>

// Problem constants
#define BATCH   16
#define SEQ     2048
#define IN_DIM  57
#define D_MODEL 64
#define HEADDIM 32
#define D_STATE 32
#define OUT_DIM 6
#define D_INNER 128
#define NHEADS  4
#define D_CONV  4
#define D_XBC   192          // D_INNER + 2*D_STATE
#define D_XD    196          // conv channels (192) + dt (4)
#define D_IN_PROJ 324        // 2*D_INNER + 2*D_STATE + NHEADS
#define BL      (BATCH*SEQ)  // 32768

// Chunked scan config
#define NCHUNK  128
#define CLEN    (SEQ / NCHUNK)   // 16

// inproj tiling
#define RTILE   24
#define XPAD    60

// Workspace layout (floats). No aliasing (phase1 reads xd AND writes sbuf).
#define OFF_WF   ((size_t)0)
#define OFF_BF   ((size_t)18496)
#define OFF_WOC  ((size_t)18848)
#define OFF_G    ((size_t)19744)
#define OFF_P    ((size_t)21792)                   // 64*128 = 8192
#define OFF_ZB   ((size_t)30016)                   // BL*128 z columns
#define OFF_XD   (OFF_ZB + (size_t)BL*D_INNER)     // BL*196 conv-in + dt raw
#define OFF_SB   (OFF_XD + (size_t)BL*D_XD)        // 64*NCHUNK*1024 chunk states
// total ≈ 19.04M floats ≈ 76 MB

// ---------------------------------------------------------------------------
// Kernel 1: Wf = W_lin@W_in ; bf = b_lin@W_in ; W_oc = W_out@W_cls.
// Also zeroes the G accumulator (ws is poisoned before every call) using
// spare thread capacity — saves a separate hipMemsetAsync dispatch.
__global__ void fuse_w_kernel(const float* __restrict__ W_lin,
                              const float* __restrict__ b_lin,
                              const float* __restrict__ W_in,
                              const float* __restrict__ W_out,
                              const float* __restrict__ W_cls,
                              float* __restrict__ Wf, float* __restrict__ bf,
                              float* __restrict__ Woc, float* __restrict__ G) {
    int idx = blockIdx.x * 256 + threadIdx.x;
    if (idx < BATCH * D_INNER) G[idx] = 0.f;
    if (idx < 58 * D_IN_PROJ) {
        int r = idx / D_IN_PROJ;
        int j = idx - r * D_IN_PROJ;
        const float* v = (r < IN_DIM) ? (W_lin + r * D_MODEL) : b_lin;
        float acc = 0.f;
#pragma unroll 8
        for (int m = 0; m < D_MODEL; ++m) acc += v[m] * W_in[m * D_IN_PROJ + j];
        if (r < IN_DIM) Wf[r * D_IN_PROJ + j] = acc;
        else            bf[j] = acc;
    } else if (idx < 58 * D_IN_PROJ + D_INNER * OUT_DIM) {
        int idx2 = idx - 58 * D_IN_PROJ;
        int i = idx2 / OUT_DIM;
        int o = idx2 - i * OUT_DIM;
        float acc = 0.f;
#pragma unroll 8
        for (int j = 0; j < D_MODEL; ++j)
            acc += W_out[i * D_MODEL + j] * W_cls[j * OUT_DIM + o];
        Woc[i * OUT_DIM + o] = acc;
    }
}

// ---------------------------------------------------------------------------
// Kernel 2: LDS-staged in-projection. Block: 24 rows x 324 cols.
// Writes z columns (0..127) to zb (stride 128), rest to xd (stride 196).
__global__ __launch_bounds__(256) void inproj_kernel(
        const float* __restrict__ x,
        const float* __restrict__ Wf,
        const float* __restrict__ bf,
        float* __restrict__ zb,
        float* __restrict__ xd) {
    __shared__ float xs[RTILE][XPAD];
    int r0 = blockIdx.x * RTILE;
    for (int i = threadIdx.x; i < RTILE * IN_DIM; i += 256) {
        size_t g = (size_t)r0 * IN_DIM + i;
        float v = (g < (size_t)BL * IN_DIM) ? x[g] : 0.f;
        xs[i / IN_DIM][i % IN_DIM] = v;
    }
    __syncthreads();
    if (threadIdx.x >= 243) return;
    int rset = threadIdx.x / 81;
    int cg   = threadIdx.x - rset * 81;
    int j0   = cg * 4;
    float4 bias = *(const float4*)(bf + j0);
    float4 acc[8];
#pragma unroll
    for (int r = 0; r < 8; ++r) acc[r] = bias;
    const float* w = Wf + j0;
    const float* xrow = &xs[rset * 8][0];
#pragma unroll 2
    for (int kc = 0; kc < 14; ++kc) {
        int k = kc * 4;
        float4 wv0 = *(const float4*)(w + (size_t)(k + 0) * D_IN_PROJ);
        float4 wv1 = *(const float4*)(w + (size_t)(k + 1) * D_IN_PROJ);
        float4 wv2 = *(const float4*)(w + (size_t)(k + 2) * D_IN_PROJ);
        float4 wv3 = *(const float4*)(w + (size_t)(k + 3) * D_IN_PROJ);
#pragma unroll
        for (int r = 0; r < 8; ++r) {
            float4 xv = *(const float4*)(xrow + r * XPAD + k);
            acc[r].x += xv.x * wv0.x + xv.y * wv1.x + xv.z * wv2.x + xv.w * wv3.x;
            acc[r].y += xv.x * wv0.y + xv.y * wv1.y + xv.z * wv2.y + xv.w * wv3.y;
            acc[r].z += xv.x * wv0.z + xv.y * wv1.z + xv.z * wv2.z + xv.w * wv3.z;
            acc[r].w += xv.x * wv0.w + xv.y * wv1.w + xv.z * wv2.w + xv.w * wv3.w;
        }
    }
    {
        float4 wv = *(const float4*)(w + (size_t)56 * D_IN_PROJ);
#pragma unroll
        for (int r = 0; r < 8; ++r) {
            float xv = xrow[r * XPAD + 56];
            acc[r].x += xv * wv.x; acc[r].y += xv * wv.y;
            acc[r].z += xv * wv.z; acc[r].w += xv * wv.w;
        }
    }
#pragma unroll
    for (int r = 0; r < 8; ++r) {
        int row = r0 + rset * 8 + r;
        if (row < BL) {
            if (j0 < D_INNER)
                *(float4*)(zb + (size_t)row * D_INNER + j0) = acc[r];
            else
                *(float4*)(xd + (size_t)row * D_XD + (j0 - D_INNER)) = acc[r];
        }
    }
}

// ---------------------------------------------------------------------------
// Conv prologue shared by phase1/phase3: 192 threads compute depthwise
// conv(4)+bias+SiLU for their channel over the chunk's 16 rows (sliding
// window, coalesced global reads); 64 threads compute {dt,dec} for one (i,h).
__device__ __forceinline__ void conv_prologue(
        const float* __restrict__ xd,
        const float* __restrict__ conv_w, const float* __restrict__ conv_b,
        const float* __restrict__ dt_bias, const float* __restrict__ A_log,
        size_t rbase, int c, int tid,
        float (*xbt)[D_XBC], float (*ddl)[8]) {
    if (tid < D_XBC) {
        int ch = tid;
        float w0 = conv_w[ch*4+0], w1 = conv_w[ch*4+1];
        float w2 = conv_w[ch*4+2], w3 = conv_w[ch*4+3];
        float cb = conv_b[ch];
        const float* src = xd + rbase * D_XD + ch;
        float vm1 = 0.f, vm2 = 0.f, vm3 = 0.f;
        if (c > 0) {
            vm1 = src[-(int)D_XD];
            vm2 = src[-2*(int)D_XD];
            vm3 = src[-3*(int)D_XD];
        }
#pragma unroll
        for (int i = 0; i < CLEN; ++i) {
            float v0 = src[(size_t)i * D_XD];
            float a = cb + v0 * w3 + vm1 * w2 + vm2 * w1 + vm3 * w0;
            xbt[i][ch] = a / (1.f + expf(-a));   // SiLU
            vm3 = vm2; vm2 = vm1; vm1 = v0;
        }
    } else {
        int idx = tid - D_XBC;       // 0..63
        int h = idx >> 4, i = idx & 15;
        float v = xd[(rbase + i) * D_XD + 192 + h] + dt_bias[h];
        float dtv = (v > 20.f) ? v : log1pf(expf(v));
        ddl[i][h * 2]     = dtv;
        ddl[i][h * 2 + 1] = expf(dtv * -expf(A_log[h]));
    }
}

// ---------------------------------------------------------------------------
// Phase 1: conv prologue -> B-scan from LDS with s0=0 -> chunk state + P.
// Wave = head; lane -> (p = lane>>1, n-half = (lane&1)*16).
__global__ __launch_bounds__(256) void scan_phase1_kernel(
        const float* __restrict__ xd,
        const float* __restrict__ conv_w, const float* __restrict__ conv_b,
        const float* __restrict__ dt_bias, const float* __restrict__ A_log,
        float* __restrict__ sbuf, float* __restrict__ Pbuf) {
    int b = blockIdx.x >> 7;          // NCHUNK=128
    int c = blockIdx.x & 127;
    int tid = threadIdx.x;
    __shared__ float xbt[CLEN][D_XBC];   // 12 KB conv outputs
    __shared__ float ddl[CLEN][8];       // 512 B {dt,dec}x4
    size_t rbase = (size_t)b * SEQ + (size_t)c * CLEN;
    conv_prologue(xd, conv_w, conv_b, dt_bias, A_log, rbase, c, tid, xbt, ddl);
    __syncthreads();
    int h = tid >> 6, lane = tid & 63;
    int p = lane >> 1, n0 = (lane & 1) * 16;
    float4 s0 = make_float4(0.f,0.f,0.f,0.f), s1 = s0, s2 = s0, s3 = s0;
    float pacc = 1.f;
#pragma unroll 4
    for (int i = 0; i < CLEN; ++i) {
        float dtv = ddl[i][h * 2];
        float dec = ddl[i][h * 2 + 1];
        float xv = xbt[i][h * HEADDIM + p];
        const float* Bp = &xbt[i][D_INNER + n0];
        float4 B0 = *(const float4*)(Bp + 0);
        float4 B1 = *(const float4*)(Bp + 4);
        float4 B2 = *(const float4*)(Bp + 8);
        float4 B3 = *(const float4*)(Bp + 12);
        float coef = dtv * xv;
        s0.x = s0.x*dec + coef*B0.x; s0.y = s0.y*dec + coef*B0.y;
        s0.z = s0.z*dec + coef*B0.z; s0.w = s0.w*dec + coef*B0.w;
        s1.x = s1.x*dec + coef*B1.x; s1.y = s1.y*dec + coef*B1.y;
        s1.z = s1.z*dec + coef*B1.z; s1.w = s1.w*dec + coef*B1.w;
        s2.x = s2.x*dec + coef*B2.x; s2.y = s2.y*dec + coef*B2.y;
        s2.z = s2.z*dec + coef*B2.z; s2.w = s2.w*dec + coef*B2.w;
        s3.x = s3.x*dec + coef*B3.x; s3.y = s3.y*dec + coef*B3.y;
        s3.z = s3.z*dec + coef*B3.z; s3.w = s3.w*dec + coef*B3.w;
        pacc *= dec;
    }
    int bh = b * NHEADS + h;
    float4* sp = (float4*)sbuf + ((size_t)bh * NCHUNK + c) * 256;
    sp[0*64 + lane] = s0;
    sp[1*64 + lane] = s1;
    sp[2*64 + lane] = s2;
    sp[3*64 + lane] = s3;
    if (lane == 0) Pbuf[bh * NCHUNK + c] = pacc;
}

// ---------------------------------------------------------------------------
// Phase 2: combine chunk states. Layout-agnostic per-(bh,c) slot scan.
__global__ __launch_bounds__(256) void scan_phase2_kernel(
        float* __restrict__ sbuf, const float* __restrict__ Pbuf) {
    int bh = blockIdx.x >> 2;
    int q  = blockIdx.x & 3;
    int idx = q * 256 + threadIdx.x;     // 0..1023
    float run = 0.f;
#pragma unroll 8
    for (int c = 0; c < NCHUNK; ++c) {
        size_t a = ((size_t)bh * NCHUNK + c) * 1024 + idx;
        float tmp = sbuf[a];
        float Pv = Pbuf[bh * NCHUNK + c];
        sbuf[a] = run;
        run = run * Pv + tmp;
    }
}

// ---------------------------------------------------------------------------
// Phase 3 (fused): conv prologue -> seeded scan from LDS -> y in LDS ->
// gate*silu(z) + RMSNorm + G accumulation. No xBC/yraw global round-trips.
__global__ __launch_bounds__(256) void scan_phase3_kernel(
        const float* __restrict__ xd,
        const float* __restrict__ conv_w, const float* __restrict__ conv_b,
        const float* __restrict__ dt_bias, const float* __restrict__ A_log,
        const float* __restrict__ zb, const float* __restrict__ Dp,
        const float* __restrict__ sbuf, const float* __restrict__ norm_w,
        float* __restrict__ G) {
    int b = blockIdx.x >> 7;          // NCHUNK=128
    int c = blockIdx.x & 127;
    int tid = threadIdx.x;
    __shared__ float xbt[CLEN][D_XBC];      // 12 KB
    __shared__ float ddl[CLEN][8];          // 512 B
    __shared__ float ylds[CLEN][D_INNER];   // 8 KB
    __shared__ float red[4][D_INNER];       // 2 KB
    size_t rbase = (size_t)b * SEQ + (size_t)c * CLEN;
    // seed load first (long-latency global, overlaps conv prologue)
    int h = tid >> 6, lane = tid & 63;
    int p = lane >> 1, n0 = (lane & 1) * 16;
    int bh = b * NHEADS + h;
    const float4* sp = (const float4*)sbuf + ((size_t)bh * NCHUNK + c) * 256;
    float4 s0 = sp[0*64 + lane];
    float4 s1 = sp[1*64 + lane];
    float4 s2 = sp[2*64 + lane];
    float4 s3 = sp[3*64 + lane];
    float Dh = Dp[h];
    conv_prologue(xd, conv_w, conv_b, dt_bias, A_log, rbase, c, tid, xbt, ddl);
    __syncthreads();
#pragma unroll 4
    for (int i = 0; i < CLEN; ++i) {
        float dtv = ddl[i][h * 2];
        float dec = ddl[i][h * 2 + 1];
        float xv = xbt[i][h * HEADDIM + p];
        const float* Bp = &xbt[i][D_INNER + n0];
        const float* Cp = &xbt[i][D_INNER + D_STATE + n0];
        float4 B0 = *(const float4*)(Bp + 0);
        float4 B1 = *(const float4*)(Bp + 4);
        float4 B2 = *(const float4*)(Bp + 8);
        float4 B3 = *(const float4*)(Bp + 12);
        float4 C0 = *(const float4*)(Cp + 0);
        float4 C1 = *(const float4*)(Cp + 4);
        float4 C2 = *(const float4*)(Cp + 8);
        float4 C3 = *(const float4*)(Cp + 12);
        float coef = dtv * xv;
        s0.x = s0.x*dec + coef*B0.x; s0.y = s0.y*dec + coef*B0.y;
        s0.z = s0.z*dec + coef*B0.z; s0.w = s0.w*dec + coef*B0.w;
        s1.x = s1.x*dec + coef*B1.x; s1.y = s1.y*dec + coef*B1.y;
        s1.z = s1.z*dec + coef*B1.z; s1.w = s1.w*dec + coef*B1.w;
        s2.x = s2.x*dec + coef*B2.x; s2.y = s2.y*dec + coef*B2.y;
        s2.z = s2.z*dec + coef*B2.z; s2.w = s2.w*dec + coef*B2.w;
        s3.x = s3.x*dec + coef*B3.x; s3.y = s3.y*dec + coef*B3.y;
        s3.z = s3.z*dec + coef*B3.z; s3.w = s3.w*dec + coef*B3.w;
        float part = s0.x*C0.x + s0.y*C0.y + s0.z*C0.z + s0.w*C0.w
                   + s1.x*C1.x + s1.y*C1.y + s1.z*C1.z + s1.w*C1.w
                   + s2.x*C2.x + s2.y*C2.y + s2.z*C2.z + s2.w*C2.w
                   + s3.x*C3.x + s3.y*C3.y + s3.z*C3.z + s3.w*C3.w;
        part += __shfl_xor(part, 1);
        if ((lane & 1) == 0)
            ylds[i][h * HEADDIM + p] = part + Dh * xv;
    }
    __syncthreads();
    // gate + RMSNorm from LDS; wave h handles rows r = h, h+4, ...
    float acc0 = 0.f, acc1 = 0.f;
    for (int r = h; r < CLEN; r += 4) {
        size_t bl = rbase + r;
        float2 yv = *(const float2*)(&ylds[r][lane * 2]);
        float2 zv = *(const float2*)(zb + bl * D_INNER + lane * 2);
        float g0 = yv.x * (zv.x / (1.f + expf(-zv.x)));
        float g1 = yv.y * (zv.y / (1.f + expf(-zv.y)));
        float sq = g0 * g0 + g1 * g1;
#pragma unroll
        for (int m = 1; m < 64; m <<= 1) sq += __shfl_xor(sq, m);
        float rms = 1.0f / sqrtf(sq * (1.f / 128.f) + 1e-5f);
        acc0 += g0 * rms;
        acc1 += g1 * rms;
    }
    red[h][lane * 2]     = acc0;
    red[h][lane * 2 + 1] = acc1;
    __syncthreads();
    if (tid < D_INNER) {
        float sg = red[0][tid] + red[1][tid] + red[2][tid] + red[3][tid];
        atomicAdd(&G[b * D_INNER + tid], sg * norm_w[tid]);
    }
}

// ---------------------------------------------------------------------------
// Kernel 6: out[b][o] = b_cls[o] + (G[b] @ W_oc)[o] / SEQ
__global__ void head_kernel(const float* __restrict__ G,
                            const float* __restrict__ Woc,
                            const float* __restrict__ b_cls,
                            float* __restrict__ out) {
    int tid = threadIdx.x;
    if (tid >= BATCH * OUT_DIM) return;
    int b = tid / OUT_DIM, o = tid - b * OUT_DIM;
    float acc = 0.f;
#pragma unroll 8
    for (int i = 0; i < D_INNER; ++i)
        acc += G[b * D_INNER + i] * Woc[i * OUT_DIM + o];
    out[b * OUT_DIM + o] = acc * (1.f / (float)SEQ) + b_cls[o];
}

// ---------------------------------------------------------------------------
extern "C" void kernel_launch(void* const* d_in, const int* in_sizes, int n_in,
                              void* d_out, int out_size, void* d_ws, size_t ws_size,
                              hipStream_t stream) {
    const float* x       = (const float*)d_in[0];
    const float* W_lin   = (const float*)d_in[1];
    const float* b_lin   = (const float*)d_in[2];
    const float* W_in    = (const float*)d_in[3];
    const float* conv_w  = (const float*)d_in[4];
    const float* conv_b  = (const float*)d_in[5];
    const float* dt_bias = (const float*)d_in[6];
    const float* A_log   = (const float*)d_in[7];
    const float* Dp      = (const float*)d_in[8];
    const float* norm_w  = (const float*)d_in[9];
    const float* W_out   = (const float*)d_in[10];
    const float* W_cls   = (const float*)d_in[11];
    const float* b_cls   = (const float*)d_in[12];
    float* out = (float*)d_out;

    float* ws = (float*)d_ws;
    float* Wf   = ws + OFF_WF;
    float* bf   = ws + OFF_BF;
    float* Woc  = ws + OFF_WOC;
    float* G    = ws + OFF_G;
    float* Pbuf = ws + OFF_P;
    float* zb   = ws + OFF_ZB;
    float* xd   = ws + OFF_XD;
    float* sbuf = ws + OFF_SB;

    // 1) fused weight precompute (also zeroes G — no separate memset)
    fuse_w_kernel<<<(58 * D_IN_PROJ + D_INNER * OUT_DIM + 255) / 256, 256, 0, stream>>>(
        W_lin, b_lin, W_in, W_out, W_cls, Wf, bf, Woc, G);

    // 2) in-projection (LDS-staged, 24 rows/block; split z / xd outputs)
    inproj_kernel<<<(BL + RTILE - 1) / RTILE, 256, 0, stream>>>(x, Wf, bf, zb, xd);

    // 3) chunked selective scan with fused conv+dt prologue (2048 blocks/phase)
    scan_phase1_kernel<<<BATCH * NCHUNK, 256, 0, stream>>>(
        xd, conv_w, conv_b, dt_bias, A_log, sbuf, Pbuf);
    scan_phase2_kernel<<<64 * 4, 256, 0, stream>>>(sbuf, Pbuf);
    scan_phase3_kernel<<<BATCH * NCHUNK, 256, 0, stream>>>(
        xd, conv_w, conv_b, dt_bias, A_log, zb, Dp, sbuf, norm_w, G);

    // 4) classifier head
    head_kernel<<<1, 128, 0, stream>>>(G, Woc, b_cls, out);
}

// Round 15
// 173.602 us; speedup vs baseline: 1.0743x; 1.0549x over previous
//
#include <hip/hip_runtime.h>
#include <hip/hip_bf16.h>
#include <hip/hip_fp16.h>
#include <cmath>

// Problem constants
#define BATCH   16
#define SEQ     2048
#define IN_DIM  57
#define D_MODEL 64
#define HEADDIM 32
#define D_STATE 32
#define OUT_DIM 6
#define D_INNER 128
#define NHEADS  4
#define D_CONV  4
#define D_XBC   192          // D_INNER + 2*D_STATE
#define D_XD    196          // conv channels (192) + dt (4)
#define D_IN_PROJ 324        // 2*D_INNER + 2*D_STATE + NHEADS
#define BL      (BATCH*SEQ)  // 32768

// Chunked scan config
#define NCHUNK  128
#define CLEN    (SEQ / NCHUNK)   // 16

// inproj tiling
#define RTILE   24
#define XPAD    60

// Workspace layout (floats). sbuf holds fp16 states (1024 halfs per (bh,c)).
#define OFF_WF   ((size_t)0)
#define OFF_BF   ((size_t)18496)
#define OFF_WOC  ((size_t)18848)
#define OFF_G    ((size_t)19744)
#define OFF_P    ((size_t)21792)                   // 64*128 = 8192
#define OFF_ZB   ((size_t)30016)                   // BL*128 z columns
#define OFF_XD   (OFF_ZB + (size_t)BL*D_INNER)     // BL*196 conv-in + dt raw
#define OFF_SB   (OFF_XD + (size_t)BL*D_XD)        // 64*NCHUNK*512 floats (fp16 x2)
// total ≈ 14.8M floats ≈ 59 MB

// ---------------------------------------------------------------------------
// Kernel 1: Wf = W_lin@W_in ; bf = b_lin@W_in ; W_oc = W_out@W_cls.
// Also zeroes the G accumulator using spare thread capacity.
__global__ void fuse_w_kernel(const float* __restrict__ W_lin,
                              const float* __restrict__ b_lin,
                              const float* __restrict__ W_in,
                              const float* __restrict__ W_out,
                              const float* __restrict__ W_cls,
                              float* __restrict__ Wf, float* __restrict__ bf,
                              float* __restrict__ Woc, float* __restrict__ G) {
    int idx = blockIdx.x * 256 + threadIdx.x;
    if (idx < BATCH * D_INNER) G[idx] = 0.f;
    if (idx < 58 * D_IN_PROJ) {
        int r = idx / D_IN_PROJ;
        int j = idx - r * D_IN_PROJ;
        const float* v = (r < IN_DIM) ? (W_lin + r * D_MODEL) : b_lin;
        float acc = 0.f;
#pragma unroll 8
        for (int m = 0; m < D_MODEL; ++m) acc += v[m] * W_in[m * D_IN_PROJ + j];
        if (r < IN_DIM) Wf[r * D_IN_PROJ + j] = acc;
        else            bf[j] = acc;
    } else if (idx < 58 * D_IN_PROJ + D_INNER * OUT_DIM) {
        int idx2 = idx - 58 * D_IN_PROJ;
        int i = idx2 / OUT_DIM;
        int o = idx2 - i * OUT_DIM;
        float acc = 0.f;
#pragma unroll 8
        for (int j = 0; j < D_MODEL; ++j)
            acc += W_out[i * D_MODEL + j] * W_cls[j * OUT_DIM + o];
        Woc[i * OUT_DIM + o] = acc;
    }
}

// ---------------------------------------------------------------------------
// Kernel 2: LDS-staged in-projection. Block: 24 rows x 324 cols.
// Writes z columns (0..127) to zb (stride 128), rest to xd (stride 196).
__global__ __launch_bounds__(256) void inproj_kernel(
        const float* __restrict__ x,
        const float* __restrict__ Wf,
        const float* __restrict__ bf,
        float* __restrict__ zb,
        float* __restrict__ xd) {
    __shared__ float xs[RTILE][XPAD];
    int r0 = blockIdx.x * RTILE;
    for (int i = threadIdx.x; i < RTILE * IN_DIM; i += 256) {
        size_t g = (size_t)r0 * IN_DIM + i;
        float v = (g < (size_t)BL * IN_DIM) ? x[g] : 0.f;
        xs[i / IN_DIM][i % IN_DIM] = v;
    }
    __syncthreads();
    if (threadIdx.x >= 243) return;
    int rset = threadIdx.x / 81;
    int cg   = threadIdx.x - rset * 81;
    int j0   = cg * 4;
    float4 bias = *(const float4*)(bf + j0);
    float4 acc[8];
#pragma unroll
    for (int r = 0; r < 8; ++r) acc[r] = bias;
    const float* w = Wf + j0;
    const float* xrow = &xs[rset * 8][0];
#pragma unroll 2
    for (int kc = 0; kc < 14; ++kc) {
        int k = kc * 4;
        float4 wv0 = *(const float4*)(w + (size_t)(k + 0) * D_IN_PROJ);
        float4 wv1 = *(const float4*)(w + (size_t)(k + 1) * D_IN_PROJ);
        float4 wv2 = *(const float4*)(w + (size_t)(k + 2) * D_IN_PROJ);
        float4 wv3 = *(const float4*)(w + (size_t)(k + 3) * D_IN_PROJ);
#pragma unroll
        for (int r = 0; r < 8; ++r) {
            float4 xv = *(const float4*)(xrow + r * XPAD + k);
            acc[r].x += xv.x * wv0.x + xv.y * wv1.x + xv.z * wv2.x + xv.w * wv3.x;
            acc[r].y += xv.x * wv0.y + xv.y * wv1.y + xv.z * wv2.y + xv.w * wv3.y;
            acc[r].z += xv.x * wv0.z + xv.y * wv1.z + xv.z * wv2.z + xv.w * wv3.z;
            acc[r].w += xv.x * wv0.w + xv.y * wv1.w + xv.z * wv2.w + xv.w * wv3.w;
        }
    }
    {
        float4 wv = *(const float4*)(w + (size_t)56 * D_IN_PROJ);
#pragma unroll
        for (int r = 0; r < 8; ++r) {
            float xv = xrow[r * XPAD + 56];
            acc[r].x += xv * wv.x; acc[r].y += xv * wv.y;
            acc[r].z += xv * wv.z; acc[r].w += xv * wv.w;
        }
    }
#pragma unroll
    for (int r = 0; r < 8; ++r) {
        int row = r0 + rset * 8 + r;
        if (row < BL) {
            if (j0 < D_INNER)
                *(float4*)(zb + (size_t)row * D_INNER + j0) = acc[r];
            else
                *(float4*)(xd + (size_t)row * D_XD + (j0 - D_INNER)) = acc[r];
        }
    }
}

// ---------------------------------------------------------------------------
// Conv prologue shared by phase1/phase3.
__device__ __forceinline__ void conv_prologue(
        const float* __restrict__ xd,
        const float* __restrict__ conv_w, const float* __restrict__ conv_b,
        const float* __restrict__ dt_bias, const float* __restrict__ A_log,
        size_t rbase, int c, int tid,
        float (*xbt)[D_XBC], float (*ddl)[8]) {
    if (tid < D_XBC) {
        int ch = tid;
        float w0 = conv_w[ch*4+0], w1 = conv_w[ch*4+1];
        float w2 = conv_w[ch*4+2], w3 = conv_w[ch*4+3];
        float cb = conv_b[ch];
        const float* src = xd + rbase * D_XD + ch;
        float vm1 = 0.f, vm2 = 0.f, vm3 = 0.f;
        if (c > 0) {
            vm1 = src[-(int)D_XD];
            vm2 = src[-2*(int)D_XD];
            vm3 = src[-3*(int)D_XD];
        }
#pragma unroll
        for (int i = 0; i < CLEN; ++i) {
            float v0 = src[(size_t)i * D_XD];
            float a = cb + v0 * w3 + vm1 * w2 + vm2 * w1 + vm3 * w0;
            xbt[i][ch] = a / (1.f + expf(-a));   // SiLU
            vm3 = vm2; vm2 = vm1; vm1 = v0;
        }
    } else {
        int idx = tid - D_XBC;       // 0..63
        int h = idx >> 4, i = idx & 15;
        float v = xd[(rbase + i) * D_XD + 192 + h] + dt_bias[h];
        float dtv = (v > 20.f) ? v : log1pf(expf(v));
        ddl[i][h * 2]     = dtv;
        ddl[i][h * 2 + 1] = expf(dtv * -expf(A_log[h]));
    }
}

// ---------------------------------------------------------------------------
// Phase 1: conv prologue -> B-scan from LDS with s0=0 -> fp16 chunk state + P.
// Wave = head; lane -> (p = lane>>1, n-half = (lane&1)*16).
// sbuf layout per (bh,c): 1024 halfs, lane-major (16 halfs per lane).
__global__ __launch_bounds__(256) void scan_phase1_kernel(
        const float* __restrict__ xd,
        const float* __restrict__ conv_w, const float* __restrict__ conv_b,
        const float* __restrict__ dt_bias, const float* __restrict__ A_log,
        __half* __restrict__ sbuf, float* __restrict__ Pbuf) {
    int b = blockIdx.x >> 7;          // NCHUNK=128
    int c = blockIdx.x & 127;
    int tid = threadIdx.x;
    __shared__ float xbt[CLEN][D_XBC];   // 12 KB conv outputs
    __shared__ float ddl[CLEN][8];       // 512 B {dt,dec}x4
    size_t rbase = (size_t)b * SEQ + (size_t)c * CLEN;
    conv_prologue(xd, conv_w, conv_b, dt_bias, A_log, rbase, c, tid, xbt, ddl);
    __syncthreads();
    int h = tid >> 6, lane = tid & 63;
    int p = lane >> 1, n0 = (lane & 1) * 16;
    float4 s0 = make_float4(0.f,0.f,0.f,0.f), s1 = s0, s2 = s0, s3 = s0;
    float pacc = 1.f;
#pragma unroll 4
    for (int i = 0; i < CLEN; ++i) {
        float dtv = ddl[i][h * 2];
        float dec = ddl[i][h * 2 + 1];
        float xv = xbt[i][h * HEADDIM + p];
        const float* Bp = &xbt[i][D_INNER + n0];
        float4 B0 = *(const float4*)(Bp + 0);
        float4 B1 = *(const float4*)(Bp + 4);
        float4 B2 = *(const float4*)(Bp + 8);
        float4 B3 = *(const float4*)(Bp + 12);
        float coef = dtv * xv;
        s0.x = s0.x*dec + coef*B0.x; s0.y = s0.y*dec + coef*B0.y;
        s0.z = s0.z*dec + coef*B0.z; s0.w = s0.w*dec + coef*B0.w;
        s1.x = s1.x*dec + coef*B1.x; s1.y = s1.y*dec + coef*B1.y;
        s1.z = s1.z*dec + coef*B1.z; s1.w = s1.w*dec + coef*B1.w;
        s2.x = s2.x*dec + coef*B2.x; s2.y = s2.y*dec + coef*B2.y;
        s2.z = s2.z*dec + coef*B2.z; s2.w = s2.w*dec + coef*B2.w;
        s3.x = s3.x*dec + coef*B3.x; s3.y = s3.y*dec + coef*B3.y;
        s3.z = s3.z*dec + coef*B3.z; s3.w = s3.w*dec + coef*B3.w;
        pacc *= dec;
    }
    int bh = b * NHEADS + h;
    __half2 hs[8];
    hs[0] = __floats2half2_rn(s0.x, s0.y); hs[1] = __floats2half2_rn(s0.z, s0.w);
    hs[2] = __floats2half2_rn(s1.x, s1.y); hs[3] = __floats2half2_rn(s1.z, s1.w);
    hs[4] = __floats2half2_rn(s2.x, s2.y); hs[5] = __floats2half2_rn(s2.z, s2.w);
    hs[6] = __floats2half2_rn(s3.x, s3.y); hs[7] = __floats2half2_rn(s3.z, s3.w);
    uint4* sp = (uint4*)(sbuf + ((size_t)bh * NCHUNK + c) * 1024) + lane * 2;
    sp[0] = *(uint4*)&hs[0];
    sp[1] = *(uint4*)&hs[4];
    if (lane == 0) Pbuf[bh * NCHUNK + c] = pacc;
}

// ---------------------------------------------------------------------------
// Phase 2: combine fp16 chunk states. Thread = one packed half2 slot
// (512 uint32 per (bh,c)); running value kept in fp32, stores quantized.
__global__ __launch_bounds__(256) void scan_phase2_kernel(
        __half* __restrict__ sbuf, const float* __restrict__ Pbuf) {
    int bh = blockIdx.x >> 1;
    int q  = blockIdx.x & 1;
    int idx = q * 256 + threadIdx.x;     // 0..511
    unsigned* s32 = (unsigned*)sbuf;
    float rx = 0.f, ry = 0.f;
#pragma unroll 8
    for (int c = 0; c < NCHUNK; ++c) {
        size_t a = ((size_t)bh * NCHUNK + c) * 512 + idx;
        unsigned v = s32[a];
        float Pv = Pbuf[bh * NCHUNK + c];
        __half2 hv = *(__half2*)&v;
        float2 t = __half22float2(hv);
        __half2 hr = __floats2half2_rn(rx, ry);
        s32[a] = *(unsigned*)&hr;
        rx = rx * Pv + t.x;
        ry = ry * Pv + t.y;
    }
}

// ---------------------------------------------------------------------------
// Phase 3 (fused): conv prologue -> seeded scan (fp16 seeds) -> y in LDS ->
// gate*silu(z) + RMSNorm + G accumulation.
__global__ __launch_bounds__(256) void scan_phase3_kernel(
        const float* __restrict__ xd,
        const float* __restrict__ conv_w, const float* __restrict__ conv_b,
        const float* __restrict__ dt_bias, const float* __restrict__ A_log,
        const float* __restrict__ zb, const float* __restrict__ Dp,
        const __half* __restrict__ sbuf, const float* __restrict__ norm_w,
        float* __restrict__ G) {
    int b = blockIdx.x >> 7;          // NCHUNK=128
    int c = blockIdx.x & 127;
    int tid = threadIdx.x;
    __shared__ float xbt[CLEN][D_XBC];      // 12 KB
    __shared__ float ddl[CLEN][8];          // 512 B
    __shared__ float ylds[CLEN][D_INNER];   // 8 KB
    __shared__ float red[4][D_INNER];       // 2 KB
    size_t rbase = (size_t)b * SEQ + (size_t)c * CLEN;
    // seed load first (long-latency global, overlaps conv prologue)
    int h = tid >> 6, lane = tid & 63;
    int p = lane >> 1, n0 = (lane & 1) * 16;
    int bh = b * NHEADS + h;
    const uint4* sp = (const uint4*)(sbuf + ((size_t)bh * NCHUNK + c) * 1024) + lane * 2;
    uint4 u0 = sp[0], u1 = sp[1];
    float Dh = Dp[h];
    conv_prologue(xd, conv_w, conv_b, dt_bias, A_log, rbase, c, tid, xbt, ddl);
    // unpack fp16 seeds -> fp32 (VALU, overlaps outstanding loads' latency)
    float4 s0, s1, s2, s3;
    {
        const __half2* hp0 = (const __half2*)&u0;
        const __half2* hp1 = (const __half2*)&u1;
        float2 f;
        f = __half22float2(hp0[0]); s0.x = f.x; s0.y = f.y;
        f = __half22float2(hp0[1]); s0.z = f.x; s0.w = f.y;
        f = __half22float2(hp0[2]); s1.x = f.x; s1.y = f.y;
        f = __half22float2(hp0[3]); s1.z = f.x; s1.w = f.y;
        f = __half22float2(hp1[0]); s2.x = f.x; s2.y = f.y;
        f = __half22float2(hp1[1]); s2.z = f.x; s2.w = f.y;
        f = __half22float2(hp1[2]); s3.x = f.x; s3.y = f.y;
        f = __half22float2(hp1[3]); s3.z = f.x; s3.w = f.y;
    }
    __syncthreads();
#pragma unroll 4
    for (int i = 0; i < CLEN; ++i) {
        float dtv = ddl[i][h * 2];
        float dec = ddl[i][h * 2 + 1];
        float xv = xbt[i][h * HEADDIM + p];
        const float* Bp = &xbt[i][D_INNER + n0];
        const float* Cp = &xbt[i][D_INNER + D_STATE + n0];
        float4 B0 = *(const float4*)(Bp + 0);
        float4 B1 = *(const float4*)(Bp + 4);
        float4 B2 = *(const float4*)(Bp + 8);
        float4 B3 = *(const float4*)(Bp + 12);
        float4 C0 = *(const float4*)(Cp + 0);
        float4 C1 = *(const float4*)(Cp + 4);
        float4 C2 = *(const float4*)(Cp + 8);
        float4 C3 = *(const float4*)(Cp + 12);
        float coef = dtv * xv;
        s0.x = s0.x*dec + coef*B0.x; s0.y = s0.y*dec + coef*B0.y;
        s0.z = s0.z*dec + coef*B0.z; s0.w = s0.w*dec + coef*B0.w;
        s1.x = s1.x*dec + coef*B1.x; s1.y = s1.y*dec + coef*B1.y;
        s1.z = s1.z*dec + coef*B1.z; s1.w = s1.w*dec + coef*B1.w;
        s2.x = s2.x*dec + coef*B2.x; s2.y = s2.y*dec + coef*B2.y;
        s2.z = s2.z*dec + coef*B2.z; s2.w = s2.w*dec + coef*B2.w;
        s3.x = s3.x*dec + coef*B3.x; s3.y = s3.y*dec + coef*B3.y;
        s3.z = s3.z*dec + coef*B3.z; s3.w = s3.w*dec + coef*B3.w;
        float part = s0.x*C0.x + s0.y*C0.y + s0.z*C0.z + s0.w*C0.w
                   + s1.x*C1.x + s1.y*C1.y + s1.z*C1.z + s1.w*C1.w
                   + s2.x*C2.x + s2.y*C2.y + s2.z*C2.z + s2.w*C2.w
                   + s3.x*C3.x + s3.y*C3.y + s3.z*C3.z + s3.w*C3.w;
        part += __shfl_xor(part, 1);
        if ((lane & 1) == 0)
            ylds[i][h * HEADDIM + p] = part + Dh * xv;
    }
    __syncthreads();
    // gate + RMSNorm from LDS; wave h handles rows r = h, h+4, ...
    float acc0 = 0.f, acc1 = 0.f;
    for (int r = h; r < CLEN; r += 4) {
        size_t bl = rbase + r;
        float2 yv = *(const float2*)(&ylds[r][lane * 2]);
        float2 zv = *(const float2*)(zb + bl * D_INNER + lane * 2);
        float g0 = yv.x * (zv.x / (1.f + expf(-zv.x)));
        float g1 = yv.y * (zv.y / (1.f + expf(-zv.y)));
        float sq = g0 * g0 + g1 * g1;
#pragma unroll
        for (int m = 1; m < 64; m <<= 1) sq += __shfl_xor(sq, m);
        float rms = 1.0f / sqrtf(sq * (1.f / 128.f) + 1e-5f);
        acc0 += g0 * rms;
        acc1 += g1 * rms;
    }
    red[h][lane * 2]     = acc0;
    red[h][lane * 2 + 1] = acc1;
    __syncthreads();
    if (tid < D_INNER) {
        float sg = red[0][tid] + red[1][tid] + red[2][tid] + red[3][tid];
        atomicAdd(&G[b * D_INNER + tid], sg * norm_w[tid]);
    }
}

// ---------------------------------------------------------------------------
// Kernel 6: out[b][o] = b_cls[o] + (G[b] @ W_oc)[o] / SEQ
__global__ void head_kernel(const float* __restrict__ G,
                            const float* __restrict__ Woc,
                            const float* __restrict__ b_cls,
                            float* __restrict__ out) {
    int tid = threadIdx.x;
    if (tid >= BATCH * OUT_DIM) return;
    int b = tid / OUT_DIM, o = tid - b * OUT_DIM;
    float acc = 0.f;
#pragma unroll 8
    for (int i = 0; i < D_INNER; ++i)
        acc += G[b * D_INNER + i] * Woc[i * OUT_DIM + o];
    out[b * OUT_DIM + o] = acc * (1.f / (float)SEQ) + b_cls[o];
}

// ---------------------------------------------------------------------------
extern "C" void kernel_launch(void* const* d_in, const int* in_sizes, int n_in,
                              void* d_out, int out_size, void* d_ws, size_t ws_size,
                              hipStream_t stream) {
    const float* x       = (const float*)d_in[0];
    const float* W_lin   = (const float*)d_in[1];
    const float* b_lin   = (const float*)d_in[2];
    const float* W_in    = (const float*)d_in[3];
    const float* conv_w  = (const float*)d_in[4];
    const float* conv_b  = (const float*)d_in[5];
    const float* dt_bias = (const float*)d_in[6];
    const float* A_log   = (const float*)d_in[7];
    const float* Dp      = (const float*)d_in[8];
    const float* norm_w  = (const float*)d_in[9];
    const float* W_out   = (const float*)d_in[10];
    const float* W_cls   = (const float*)d_in[11];
    const float* b_cls   = (const float*)d_in[12];
    float* out = (float*)d_out;

    float* ws = (float*)d_ws;
    float* Wf   = ws + OFF_WF;
    float* bf   = ws + OFF_BF;
    float* Woc  = ws + OFF_WOC;
    float* G    = ws + OFF_G;
    float* Pbuf = ws + OFF_P;
    float* zb   = ws + OFF_ZB;
    float* xd   = ws + OFF_XD;
    __half* sbuf = (__half*)(ws + OFF_SB);

    // 1) fused weight precompute (also zeroes G — no separate memset)
    fuse_w_kernel<<<(58 * D_IN_PROJ + D_INNER * OUT_DIM + 255) / 256, 256, 0, stream>>>(
        W_lin, b_lin, W_in, W_out, W_cls, Wf, bf, Woc, G);

    // 2) in-projection (LDS-staged, 24 rows/block; split z / xd outputs)
    inproj_kernel<<<(BL + RTILE - 1) / RTILE, 256, 0, stream>>>(x, Wf, bf, zb, xd);

    // 3) chunked selective scan with fused conv+dt prologue (2048 blocks/phase);
    //    fp16 chunk states halve sbuf traffic.
    scan_phase1_kernel<<<BATCH * NCHUNK, 256, 0, stream>>>(
        xd, conv_w, conv_b, dt_bias, A_log, sbuf, Pbuf);
    scan_phase2_kernel<<<64 * 2, 256, 0, stream>>>(sbuf, Pbuf);
    scan_phase3_kernel<<<BATCH * NCHUNK, 256, 0, stream>>>(
        xd, conv_w, conv_b, dt_bias, A_log, zb, Dp, sbuf, norm_w, G);

    // 4) classifier head
    head_kernel<<<1, 128, 0, stream>>>(G, Woc, b_cls, out);
}

// Round 16
// 169.090 us; speedup vs baseline: 1.1029x; 1.0267x over previous
//
#include <hip/hip_runtime.h>
#include <hip/hip_bf16.h>
#include <hip/hip_fp16.h>
#include <cmath>

// Problem constants
#define BATCH   16
#define SEQ     2048
#define IN_DIM  57
#define D_MODEL 64
#define HEADDIM 32
#define D_STATE 32
#define OUT_DIM 6
#define D_INNER 128
#define NHEADS  4
#define D_CONV  4
#define D_XBC   192          // D_INNER + 2*D_STATE
#define D_XD    196          // conv channels (192) + dt (4)
#define D_IN_PROJ 324        // 2*D_INNER + 2*D_STATE + NHEADS
#define BL      (BATCH*SEQ)  // 32768

// Chunked scan config
#define NCHUNK  128
#define CLEN    (SEQ / NCHUNK)   // 16

// inproj tiling
#define RTILE   24
#define XPAD    60

// Workspace layout (floats). zb/xd/sbuf hold fp16 (2 halfs per float slot).
#define OFF_WF   ((size_t)0)
#define OFF_BF   ((size_t)18496)
#define OFF_WOC  ((size_t)18848)
#define OFF_G    ((size_t)19744)
#define OFF_P    ((size_t)21792)                    // 64*128 = 8192
#define OFF_ZB   ((size_t)30016)                    // BL*128 halfs = BL*64 floats
#define OFF_XD   (OFF_ZB + (size_t)BL*64)           // BL*196 halfs = BL*98 floats
#define OFF_SB   (OFF_XD + (size_t)BL*98)           // 64*128*1024 halfs
// total ≈ 9.6M floats ≈ 38 MB

// ---------------------------------------------------------------------------
// Kernel 1: Wf = W_lin@W_in ; bf = b_lin@W_in ; W_oc = W_out@W_cls.
// Also zeroes the G accumulator using spare thread capacity.
__global__ void fuse_w_kernel(const float* __restrict__ W_lin,
                              const float* __restrict__ b_lin,
                              const float* __restrict__ W_in,
                              const float* __restrict__ W_out,
                              const float* __restrict__ W_cls,
                              float* __restrict__ Wf, float* __restrict__ bf,
                              float* __restrict__ Woc, float* __restrict__ G) {
    int idx = blockIdx.x * 256 + threadIdx.x;
    if (idx < BATCH * D_INNER) G[idx] = 0.f;
    if (idx < 58 * D_IN_PROJ) {
        int r = idx / D_IN_PROJ;
        int j = idx - r * D_IN_PROJ;
        const float* v = (r < IN_DIM) ? (W_lin + r * D_MODEL) : b_lin;
        float acc = 0.f;
#pragma unroll 8
        for (int m = 0; m < D_MODEL; ++m) acc += v[m] * W_in[m * D_IN_PROJ + j];
        if (r < IN_DIM) Wf[r * D_IN_PROJ + j] = acc;
        else            bf[j] = acc;
    } else if (idx < 58 * D_IN_PROJ + D_INNER * OUT_DIM) {
        int idx2 = idx - 58 * D_IN_PROJ;
        int i = idx2 / OUT_DIM;
        int o = idx2 - i * OUT_DIM;
        float acc = 0.f;
#pragma unroll 8
        for (int j = 0; j < D_MODEL; ++j)
            acc += W_out[i * D_MODEL + j] * W_cls[j * OUT_DIM + o];
        Woc[i * OUT_DIM + o] = acc;
    }
}

// ---------------------------------------------------------------------------
// Kernel 2: LDS-staged in-projection. Block: 24 rows x 324 cols.
// Outputs quantized to fp16: z cols (0..127) -> zbh (stride 128 halfs),
// conv-in + dt cols -> xdh (stride 196 halfs).
__global__ __launch_bounds__(256) void inproj_kernel(
        const float* __restrict__ x,
        const float* __restrict__ Wf,
        const float* __restrict__ bf,
        __half* __restrict__ zbh,
        __half* __restrict__ xdh) {
    __shared__ float xs[RTILE][XPAD];
    int r0 = blockIdx.x * RTILE;
    for (int i = threadIdx.x; i < RTILE * IN_DIM; i += 256) {
        size_t g = (size_t)r0 * IN_DIM + i;
        float v = (g < (size_t)BL * IN_DIM) ? x[g] : 0.f;
        xs[i / IN_DIM][i % IN_DIM] = v;
    }
    __syncthreads();
    if (threadIdx.x >= 243) return;
    int rset = threadIdx.x / 81;
    int cg   = threadIdx.x - rset * 81;
    int j0   = cg * 4;
    float4 bias = *(const float4*)(bf + j0);
    float4 acc[8];
#pragma unroll
    for (int r = 0; r < 8; ++r) acc[r] = bias;
    const float* w = Wf + j0;
    const float* xrow = &xs[rset * 8][0];
#pragma unroll 2
    for (int kc = 0; kc < 14; ++kc) {
        int k = kc * 4;
        float4 wv0 = *(const float4*)(w + (size_t)(k + 0) * D_IN_PROJ);
        float4 wv1 = *(const float4*)(w + (size_t)(k + 1) * D_IN_PROJ);
        float4 wv2 = *(const float4*)(w + (size_t)(k + 2) * D_IN_PROJ);
        float4 wv3 = *(const float4*)(w + (size_t)(k + 3) * D_IN_PROJ);
#pragma unroll
        for (int r = 0; r < 8; ++r) {
            float4 xv = *(const float4*)(xrow + r * XPAD + k);
            acc[r].x += xv.x * wv0.x + xv.y * wv1.x + xv.z * wv2.x + xv.w * wv3.x;
            acc[r].y += xv.x * wv0.y + xv.y * wv1.y + xv.z * wv2.y + xv.w * wv3.y;
            acc[r].z += xv.x * wv0.z + xv.y * wv1.z + xv.z * wv2.z + xv.w * wv3.z;
            acc[r].w += xv.x * wv0.w + xv.y * wv1.w + xv.z * wv2.w + xv.w * wv3.w;
        }
    }
    {
        float4 wv = *(const float4*)(w + (size_t)56 * D_IN_PROJ);
#pragma unroll
        for (int r = 0; r < 8; ++r) {
            float xv = xrow[r * XPAD + 56];
            acc[r].x += xv * wv.x; acc[r].y += xv * wv.y;
            acc[r].z += xv * wv.z; acc[r].w += xv * wv.w;
        }
    }
#pragma unroll
    for (int r = 0; r < 8; ++r) {
        int row = r0 + rset * 8 + r;
        if (row < BL) {
            __half2 h01 = __floats2half2_rn(acc[r].x, acc[r].y);
            __half2 h23 = __floats2half2_rn(acc[r].z, acc[r].w);
            uint2 u;
            u.x = *(unsigned*)&h01;
            u.y = *(unsigned*)&h23;
            if (j0 < D_INNER)
                *(uint2*)(zbh + (size_t)row * D_INNER + j0) = u;
            else
                *(uint2*)(xdh + (size_t)row * D_XD + (j0 - D_INNER)) = u;
        }
    }
}

// ---------------------------------------------------------------------------
// Conv prologue shared by phase1/phase3 (fp16 xd input, fp32 compute).
__device__ __forceinline__ void conv_prologue(
        const __half* __restrict__ xdh,
        const float* __restrict__ conv_w, const float* __restrict__ conv_b,
        const float* __restrict__ dt_bias, const float* __restrict__ A_log,
        size_t rbase, int c, int tid,
        float (*xbt)[D_XBC], float (*ddl)[8]) {
    if (tid < D_XBC) {
        int ch = tid;
        float w0 = conv_w[ch*4+0], w1 = conv_w[ch*4+1];
        float w2 = conv_w[ch*4+2], w3 = conv_w[ch*4+3];
        float cb = conv_b[ch];
        const __half* src = xdh + rbase * D_XD + ch;
        float vm1 = 0.f, vm2 = 0.f, vm3 = 0.f;
        if (c > 0) {
            vm1 = __half2float(src[-(int)D_XD]);
            vm2 = __half2float(src[-2*(int)D_XD]);
            vm3 = __half2float(src[-3*(int)D_XD]);
        }
#pragma unroll
        for (int i = 0; i < CLEN; ++i) {
            float v0 = __half2float(src[(size_t)i * D_XD]);
            float a = cb + v0 * w3 + vm1 * w2 + vm2 * w1 + vm3 * w0;
            xbt[i][ch] = a / (1.f + expf(-a));   // SiLU
            vm3 = vm2; vm2 = vm1; vm1 = v0;
        }
    } else {
        int idx = tid - D_XBC;       // 0..63
        int h = idx >> 4, i = idx & 15;
        float v = __half2float(xdh[(rbase + i) * D_XD + 192 + h]) + dt_bias[h];
        float dtv = (v > 20.f) ? v : log1pf(expf(v));
        ddl[i][h * 2]     = dtv;
        ddl[i][h * 2 + 1] = expf(dtv * -expf(A_log[h]));
    }
}

// ---------------------------------------------------------------------------
// Phase 1: conv prologue -> B-scan from LDS with s0=0 -> fp16 chunk state + P.
__global__ __launch_bounds__(256) void scan_phase1_kernel(
        const __half* __restrict__ xdh,
        const float* __restrict__ conv_w, const float* __restrict__ conv_b,
        const float* __restrict__ dt_bias, const float* __restrict__ A_log,
        __half* __restrict__ sbuf, float* __restrict__ Pbuf) {
    int b = blockIdx.x >> 7;          // NCHUNK=128
    int c = blockIdx.x & 127;
    int tid = threadIdx.x;
    __shared__ float xbt[CLEN][D_XBC];   // 12 KB conv outputs
    __shared__ float ddl[CLEN][8];       // 512 B {dt,dec}x4
    size_t rbase = (size_t)b * SEQ + (size_t)c * CLEN;
    conv_prologue(xdh, conv_w, conv_b, dt_bias, A_log, rbase, c, tid, xbt, ddl);
    __syncthreads();
    int h = tid >> 6, lane = tid & 63;
    int p = lane >> 1, n0 = (lane & 1) * 16;
    float4 s0 = make_float4(0.f,0.f,0.f,0.f), s1 = s0, s2 = s0, s3 = s0;
    float pacc = 1.f;
#pragma unroll 4
    for (int i = 0; i < CLEN; ++i) {
        float dtv = ddl[i][h * 2];
        float dec = ddl[i][h * 2 + 1];
        float xv = xbt[i][h * HEADDIM + p];
        const float* Bp = &xbt[i][D_INNER + n0];
        float4 B0 = *(const float4*)(Bp + 0);
        float4 B1 = *(const float4*)(Bp + 4);
        float4 B2 = *(const float4*)(Bp + 8);
        float4 B3 = *(const float4*)(Bp + 12);
        float coef = dtv * xv;
        s0.x = s0.x*dec + coef*B0.x; s0.y = s0.y*dec + coef*B0.y;
        s0.z = s0.z*dec + coef*B0.z; s0.w = s0.w*dec + coef*B0.w;
        s1.x = s1.x*dec + coef*B1.x; s1.y = s1.y*dec + coef*B1.y;
        s1.z = s1.z*dec + coef*B1.z; s1.w = s1.w*dec + coef*B1.w;
        s2.x = s2.x*dec + coef*B2.x; s2.y = s2.y*dec + coef*B2.y;
        s2.z = s2.z*dec + coef*B2.z; s2.w = s2.w*dec + coef*B2.w;
        s3.x = s3.x*dec + coef*B3.x; s3.y = s3.y*dec + coef*B3.y;
        s3.z = s3.z*dec + coef*B3.z; s3.w = s3.w*dec + coef*B3.w;
        pacc *= dec;
    }
    int bh = b * NHEADS + h;
    __half2 hs[8];
    hs[0] = __floats2half2_rn(s0.x, s0.y); hs[1] = __floats2half2_rn(s0.z, s0.w);
    hs[2] = __floats2half2_rn(s1.x, s1.y); hs[3] = __floats2half2_rn(s1.z, s1.w);
    hs[4] = __floats2half2_rn(s2.x, s2.y); hs[5] = __floats2half2_rn(s2.z, s2.w);
    hs[6] = __floats2half2_rn(s3.x, s3.y); hs[7] = __floats2half2_rn(s3.z, s3.w);
    uint4* sp = (uint4*)(sbuf + ((size_t)bh * NCHUNK + c) * 1024) + lane * 2;
    sp[0] = *(uint4*)&hs[0];
    sp[1] = *(uint4*)&hs[4];
    if (lane == 0) Pbuf[bh * NCHUNK + c] = pacc;
}

// ---------------------------------------------------------------------------
// Phase 2: combine fp16 chunk states; running value fp32, stores quantized.
__global__ __launch_bounds__(256) void scan_phase2_kernel(
        __half* __restrict__ sbuf, const float* __restrict__ Pbuf) {
    int bh = blockIdx.x >> 1;
    int q  = blockIdx.x & 1;
    int idx = q * 256 + threadIdx.x;     // 0..511
    unsigned* s32 = (unsigned*)sbuf;
    float rx = 0.f, ry = 0.f;
#pragma unroll 8
    for (int c = 0; c < NCHUNK; ++c) {
        size_t a = ((size_t)bh * NCHUNK + c) * 512 + idx;
        unsigned v = s32[a];
        float Pv = Pbuf[bh * NCHUNK + c];
        __half2 hv = *(__half2*)&v;
        float2 t = __half22float2(hv);
        __half2 hr = __floats2half2_rn(rx, ry);
        s32[a] = *(unsigned*)&hr;
        rx = rx * Pv + t.x;
        ry = ry * Pv + t.y;
    }
}

// ---------------------------------------------------------------------------
// Phase 3 (fused): conv prologue -> seeded scan (fp16 seeds) -> y in LDS ->
// gate*silu(z) (fp16 z) + RMSNorm + G accumulation.
__global__ __launch_bounds__(256) void scan_phase3_kernel(
        const __half* __restrict__ xdh,
        const float* __restrict__ conv_w, const float* __restrict__ conv_b,
        const float* __restrict__ dt_bias, const float* __restrict__ A_log,
        const __half* __restrict__ zbh, const float* __restrict__ Dp,
        const __half* __restrict__ sbuf, const float* __restrict__ norm_w,
        float* __restrict__ G) {
    int b = blockIdx.x >> 7;          // NCHUNK=128
    int c = blockIdx.x & 127;
    int tid = threadIdx.x;
    __shared__ float xbt[CLEN][D_XBC];      // 12 KB
    __shared__ float ddl[CLEN][8];          // 512 B
    __shared__ float ylds[CLEN][D_INNER];   // 8 KB
    __shared__ float red[4][D_INNER];       // 2 KB
    size_t rbase = (size_t)b * SEQ + (size_t)c * CLEN;
    // seed load first (long-latency global, overlaps conv prologue)
    int h = tid >> 6, lane = tid & 63;
    int p = lane >> 1, n0 = (lane & 1) * 16;
    int bh = b * NHEADS + h;
    const uint4* sp = (const uint4*)(sbuf + ((size_t)bh * NCHUNK + c) * 1024) + lane * 2;
    uint4 u0 = sp[0], u1 = sp[1];
    float Dh = Dp[h];
    conv_prologue(xdh, conv_w, conv_b, dt_bias, A_log, rbase, c, tid, xbt, ddl);
    // unpack fp16 seeds -> fp32
    float4 s0, s1, s2, s3;
    {
        const __half2* hp0 = (const __half2*)&u0;
        const __half2* hp1 = (const __half2*)&u1;
        float2 f;
        f = __half22float2(hp0[0]); s0.x = f.x; s0.y = f.y;
        f = __half22float2(hp0[1]); s0.z = f.x; s0.w = f.y;
        f = __half22float2(hp0[2]); s1.x = f.x; s1.y = f.y;
        f = __half22float2(hp0[3]); s1.z = f.x; s1.w = f.y;
        f = __half22float2(hp1[0]); s2.x = f.x; s2.y = f.y;
        f = __half22float2(hp1[1]); s2.z = f.x; s2.w = f.y;
        f = __half22float2(hp1[2]); s3.x = f.x; s3.y = f.y;
        f = __half22float2(hp1[3]); s3.z = f.x; s3.w = f.y;
    }
    __syncthreads();
#pragma unroll 4
    for (int i = 0; i < CLEN; ++i) {
        float dtv = ddl[i][h * 2];
        float dec = ddl[i][h * 2 + 1];
        float xv = xbt[i][h * HEADDIM + p];
        const float* Bp = &xbt[i][D_INNER + n0];
        const float* Cp = &xbt[i][D_INNER + D_STATE + n0];
        float4 B0 = *(const float4*)(Bp + 0);
        float4 B1 = *(const float4*)(Bp + 4);
        float4 B2 = *(const float4*)(Bp + 8);
        float4 B3 = *(const float4*)(Bp + 12);
        float4 C0 = *(const float4*)(Cp + 0);
        float4 C1 = *(const float4*)(Cp + 4);
        float4 C2 = *(const float4*)(Cp + 8);
        float4 C3 = *(const float4*)(Cp + 12);
        float coef = dtv * xv;
        s0.x = s0.x*dec + coef*B0.x; s0.y = s0.y*dec + coef*B0.y;
        s0.z = s0.z*dec + coef*B0.z; s0.w = s0.w*dec + coef*B0.w;
        s1.x = s1.x*dec + coef*B1.x; s1.y = s1.y*dec + coef*B1.y;
        s1.z = s1.z*dec + coef*B1.z; s1.w = s1.w*dec + coef*B1.w;
        s2.x = s2.x*dec + coef*B2.x; s2.y = s2.y*dec + coef*B2.y;
        s2.z = s2.z*dec + coef*B2.z; s2.w = s2.w*dec + coef*B2.w;
        s3.x = s3.x*dec + coef*B3.x; s3.y = s3.y*dec + coef*B3.y;
        s3.z = s3.z*dec + coef*B3.z; s3.w = s3.w*dec + coef*B3.w;
        float part = s0.x*C0.x + s0.y*C0.y + s0.z*C0.z + s0.w*C0.w
                   + s1.x*C1.x + s1.y*C1.y + s1.z*C1.z + s1.w*C1.w
                   + s2.x*C2.x + s2.y*C2.y + s2.z*C2.z + s2.w*C2.w
                   + s3.x*C3.x + s3.y*C3.y + s3.z*C3.z + s3.w*C3.w;
        part += __shfl_xor(part, 1);
        if ((lane & 1) == 0)
            ylds[i][h * HEADDIM + p] = part + Dh * xv;
    }
    __syncthreads();
    // gate + RMSNorm from LDS; wave h handles rows r = h, h+4, ...
    float acc0 = 0.f, acc1 = 0.f;
    for (int r = h; r < CLEN; r += 4) {
        size_t bl = rbase + r;
        float2 yv = *(const float2*)(&ylds[r][lane * 2]);
        float2 zv = __half22float2(*((const __half2*)(zbh + bl * D_INNER) + lane));
        float g0 = yv.x * (zv.x / (1.f + expf(-zv.x)));
        float g1 = yv.y * (zv.y / (1.f + expf(-zv.y)));
        float sq = g0 * g0 + g1 * g1;
#pragma unroll
        for (int m = 1; m < 64; m <<= 1) sq += __shfl_xor(sq, m);
        float rms = 1.0f / sqrtf(sq * (1.f / 128.f) + 1e-5f);
        acc0 += g0 * rms;
        acc1 += g1 * rms;
    }
    red[h][lane * 2]     = acc0;
    red[h][lane * 2 + 1] = acc1;
    __syncthreads();
    if (tid < D_INNER) {
        float sg = red[0][tid] + red[1][tid] + red[2][tid] + red[3][tid];
        atomicAdd(&G[b * D_INNER + tid], sg * norm_w[tid]);
    }
}

// ---------------------------------------------------------------------------
// Kernel 6: out[b][o] = b_cls[o] + (G[b] @ W_oc)[o] / SEQ
__global__ void head_kernel(const float* __restrict__ G,
                            const float* __restrict__ Woc,
                            const float* __restrict__ b_cls,
                            float* __restrict__ out) {
    int tid = threadIdx.x;
    if (tid >= BATCH * OUT_DIM) return;
    int b = tid / OUT_DIM, o = tid - b * OUT_DIM;
    float acc = 0.f;
#pragma unroll 8
    for (int i = 0; i < D_INNER; ++i)
        acc += G[b * D_INNER + i] * Woc[i * OUT_DIM + o];
    out[b * OUT_DIM + o] = acc * (1.f / (float)SEQ) + b_cls[o];
}

// ---------------------------------------------------------------------------
extern "C" void kernel_launch(void* const* d_in, const int* in_sizes, int n_in,
                              void* d_out, int out_size, void* d_ws, size_t ws_size,
                              hipStream_t stream) {
    const float* x       = (const float*)d_in[0];
    const float* W_lin   = (const float*)d_in[1];
    const float* b_lin   = (const float*)d_in[2];
    const float* W_in    = (const float*)d_in[3];
    const float* conv_w  = (const float*)d_in[4];
    const float* conv_b  = (const float*)d_in[5];
    const float* dt_bias = (const float*)d_in[6];
    const float* A_log   = (const float*)d_in[7];
    const float* Dp      = (const float*)d_in[8];
    const float* norm_w  = (const float*)d_in[9];
    const float* W_out   = (const float*)d_in[10];
    const float* W_cls   = (const float*)d_in[11];
    const float* b_cls   = (const float*)d_in[12];
    float* out = (float*)d_out;

    float* ws = (float*)d_ws;
    float* Wf    = ws + OFF_WF;
    float* bf    = ws + OFF_BF;
    float* Woc   = ws + OFF_WOC;
    float* G     = ws + OFF_G;
    float* Pbuf  = ws + OFF_P;
    __half* zbh  = (__half*)(ws + OFF_ZB);
    __half* xdh  = (__half*)(ws + OFF_XD);
    __half* sbuf = (__half*)(ws + OFF_SB);

    // 1) fused weight precompute (also zeroes G — no separate memset)
    fuse_w_kernel<<<(58 * D_IN_PROJ + D_INNER * OUT_DIM + 255) / 256, 256, 0, stream>>>(
        W_lin, b_lin, W_in, W_out, W_cls, Wf, bf, Woc, G);

    // 2) in-projection (LDS-staged, 24 rows/block; fp16 z / xd outputs)
    inproj_kernel<<<(BL + RTILE - 1) / RTILE, 256, 0, stream>>>(x, Wf, bf, zbh, xdh);

    // 3) chunked selective scan with fused conv+dt prologue (2048 blocks/phase);
    //    fp16 xd/zb/sbuf halve all bulk intermediate traffic.
    scan_phase1_kernel<<<BATCH * NCHUNK, 256, 0, stream>>>(
        xdh, conv_w, conv_b, dt_bias, A_log, sbuf, Pbuf);
    scan_phase2_kernel<<<64 * 2, 256, 0, stream>>>(sbuf, Pbuf);
    scan_phase3_kernel<<<BATCH * NCHUNK, 256, 0, stream>>>(
        xdh, conv_w, conv_b, dt_bias, A_log, zbh, Dp, sbuf, norm_w, G);

    // 4) classifier head
    head_kernel<<<1, 128, 0, stream>>>(G, Woc, b_cls, out);
}